// Round 1
// baseline (2654.839 us; speedup 1.0000x reference)
//
#include <hip/hip_runtime.h>
#include <math.h>

// Problem constants
#define B_        256
#define F_        512
#define T_        81
#define WIN_      1022
#define HOP_      400
#define NF_       69
#define OUT_LEN_  28550
#define SEG_      1000
#define OVL_      50

// Workspace layout (float offsets)
#define SYNWIN_OFF_ 0            // 1022 floats
#define HANN_OFF_   1024         // 1022 floats
#define TF_OFF_     4096         // 20736 * 1024 floats
#define TF_FRAME_   1024
#define OUTF_OFF_   (TF_OFF_ + B_*T_*TF_FRAME_)   // 256 * 28672 floats
#define OUTF_STRIDE_ 28672

// ---------------------------------------------------------------------------
// K1: build synthesis window and hann window tables
// ---------------------------------------------------------------------------
__global__ __launch_bounds__(256) void k1_tables(float* __restrict__ ws) {
  int i = blockIdx.x * 256 + threadIdx.x;
  if (i >= WIN_) return;
  const float twopi_N = 6.283185307179586f / (float)WIN_;
  float w = 0.5f - 0.5f * cosf(twopi_N * (float)i);
  // denom[j] = sum of hann^2 at j, j+400, j+800 (zero-padded past 1021)
  int j = i % HOP_;
  float a = 0.5f - 0.5f * cosf(twopi_N * (float)j);
  float b = 0.5f - 0.5f * cosf(twopi_N * (float)(j + 400));
  float d = a * a + b * b;
  if (j + 800 < WIN_) {
    float c = 0.5f - 0.5f * cosf(twopi_N * (float)(j + 800));
    d += c * c;
  }
  ws[SYNWIN_OFF_ + i] = w / d;
  ws[HANN_OFF_ + i]   = w;
}

// ---------------------------------------------------------------------------
// K2: inverse rDFT per (b,t) frame + synthesis window -> tf buffer
//   y[n] = (X0r + (-1)^n X511r + 2*sum_{k=1..510}(Xkr cos - Xki sin)) * synwin[n] / N
// One block per frame; thread handles 4 consecutive n via phase recurrence.
// ---------------------------------------------------------------------------
__global__ __launch_bounds__(256) void k2_idft(const float* __restrict__ x,
                                               const float* __restrict__ ws,
                                               float* __restrict__ tf) {
  __shared__ float2 Xc[F_];
  int bt = blockIdx.x;           // b*81 + t
  int b = bt / T_;
  int t = bt - b * T_;
  for (int k = threadIdx.x; k < F_; k += 256) {
    const float* p = x + (((size_t)(b * F_ + k)) * T_ + t) * 2;
    Xc[k] = make_float2(p[0], p[1]);
  }
  __syncthreads();

  float dc = Xc[0].x;
  float ny = Xc[511].x;
  int n0 = threadIdx.x * 4;
  const float twopi_N = 6.283185307179586f / (float)WIN_;

  float accr[4], c[4], s[4], wr[4], wi[4];
#pragma unroll
  for (int j = 0; j < 4; ++j) {
    float ang = twopi_N * (float)(n0 + j);
    float sv, cv;
    sincosf(ang, &sv, &cv);
    wr[j] = cv; wi[j] = sv;     // rotation unit e^{i*2pi*n/N}
    c[j] = cv;  s[j] = sv;      // phase at k=1
    accr[j] = 0.f;
  }

  for (int k = 1; k <= 510; ++k) {
    float2 X = Xc[k];
#pragma unroll
    for (int j = 0; j < 4; ++j) {
      accr[j] = fmaf(X.x, c[j], accr[j]);
      accr[j] = fmaf(-X.y, s[j], accr[j]);
      float cn = fmaf(c[j], wr[j], -(s[j] * wi[j]));
      float sn = fmaf(c[j], wi[j],  (s[j] * wr[j]));
      c[j] = cn; s[j] = sn;
    }
  }

  float* dst = tf + (size_t)bt * TF_FRAME_;
#pragma unroll
  for (int j = 0; j < 4; ++j) {
    int n = n0 + j;
    if (n < WIN_) {
      float v = dc + ((n & 1) ? -ny : ny) + 2.f * accr[j];
      dst[n] = v * (1.0f / (float)WIN_) * ws[SYNWIN_OFF_ + n];
    }
  }
}

// ---------------------------------------------------------------------------
// K3: overlap-add (gather) + keep + crossfade -> outf buffer
// ---------------------------------------------------------------------------
__device__ __forceinline__ float sigval(const float* __restrict__ tfb, int i) {
  // sig[i] = sum over frames t with 0 <= i - 400t <= 1021
  int t1 = i / HOP_;
  if (t1 > T_ - 1) t1 = T_ - 1;
  int t0 = (i >= WIN_) ? (i - (WIN_ - 1) + HOP_ - 1) / HOP_ : 0;  // ceil((i-1021)/400)
  float acc = 0.f;
  for (int t = t0; t <= t1; ++t)
    acc += tfb[t * TF_FRAME_ + (i - t * HOP_)];
  return acc;
}

__global__ __launch_bounds__(256) void k3_fold(const float* __restrict__ tf,
                                               float* __restrict__ outf) {
  int id = blockIdx.x * 256 + threadIdx.x;
  if (id >= B_ * OUT_LEN_) return;
  int b = id / OUT_LEN_;
  int p = id - b * OUT_LEN_;

  // map final index p -> kept index j = s*1000 + r  (FINAL_KEEP inverse)
  int s, r;
  if (p < SEG_) { s = 0; r = p; }
  else {
    int q = p - SEG_;
    s = q / (SEG_ - OVL_) + 1;
    r = OVL_ + (q - (s - 1) * (SEG_ - OVL_));
  }

  const float* tfb = tf + (size_t)b * T_ * TF_FRAME_;
  float val;
  if (r >= SEG_ - OVL_ && s <= 28) {
    // crossfade: (1000-r)/50 * kept[j] + (r-949)/50 * kept[j+50]
    float dec = (float)(SEG_ - r) * (1.f / (float)OVL_);
    float inc = (float)(r - (SEG_ - OVL_ - 1)) * (1.f / (float)OVL_);
    float v1 = sigval(tfb, s * 1100 + r);
    float v2 = sigval(tfb, (s + 1) * 1100 + (r - (SEG_ - OVL_)));
    val = dec * v1 + inc * v2;
  } else {
    val = sigval(tfb, s * 1100 + r);
  }
  outf[(size_t)b * OUTF_STRIDE_ + p] = val;
}

// ---------------------------------------------------------------------------
// K4: forward rDFT per (b,f) frame (hann applied on load) -> d_out
//   S[k] = sum_w fr[w] e^{-2pi i k w / N};  out[b,k,f,0]=Re, [.,1]=Im
// One block per (b,f); thread handles k = tid and tid+256 via recurrence.
// ---------------------------------------------------------------------------
__global__ __launch_bounds__(256) void k4_dft(const float* __restrict__ ws,
                                              const float* __restrict__ outf,
                                              float* __restrict__ out) {
  __shared__ float fr[WIN_];
  int bf = blockIdx.x;
  int b = bf / NF_;
  int f = bf - b * NF_;
  const float* src = outf + (size_t)b * OUTF_STRIDE_ + f * HOP_;
  for (int w = threadIdx.x; w < WIN_; w += 256)
    fr[w] = src[w] * ws[HANN_OFF_ + w];
  __syncthreads();

  const float twopi_N = 6.283185307179586f / (float)WIN_;
  float ar[2] = {0.f, 0.f}, ai[2] = {0.f, 0.f};
  float c[2], s[2], wr[2], wi[2];
#pragma unroll
  for (int j = 0; j < 2; ++j) {
    int k = threadIdx.x + j * 256;
    float ang = twopi_N * (float)k;
    float sv, cv;
    sincosf(ang, &sv, &cv);
    wr[j] = cv; wi[j] = -sv;    // rotation unit e^{-i*2pi*k/N}
    c[j] = 1.f; s[j] = 0.f;     // phase at w=0
  }

  for (int w = 0; w < WIN_; ++w) {
    float v = fr[w];
#pragma unroll
    for (int j = 0; j < 2; ++j) {
      ar[j] = fmaf(v, c[j], ar[j]);
      ai[j] = fmaf(v, s[j], ai[j]);
      float cn = fmaf(c[j], wr[j], -(s[j] * wi[j]));
      float sn = fmaf(c[j], wi[j],  (s[j] * wr[j]));
      c[j] = cn; s[j] = sn;
    }
  }

#pragma unroll
  for (int j = 0; j < 2; ++j) {
    int k = threadIdx.x + j * 256;
    float* dst = out + (((size_t)b * F_ + k) * NF_ + f) * 2;
    dst[0] = ar[j];
    dst[1] = ai[j];
  }
}

// ---------------------------------------------------------------------------
extern "C" void kernel_launch(void* const* d_in, const int* in_sizes, int n_in,
                              void* d_out, int out_size, void* d_ws, size_t ws_size,
                              hipStream_t stream) {
  const float* x = (const float*)d_in[0];
  float* out = (float*)d_out;
  float* ws = (float*)d_ws;

  hipLaunchKernelGGL(k1_tables, dim3(4), dim3(256), 0, stream, ws);
  hipLaunchKernelGGL(k2_idft, dim3(B_ * T_), dim3(256), 0, stream,
                     x, ws, ws + TF_OFF_);
  int n3 = B_ * OUT_LEN_;
  hipLaunchKernelGGL(k3_fold, dim3((n3 + 255) / 256), dim3(256), 0, stream,
                     ws + TF_OFF_, ws + OUTF_OFF_);
  hipLaunchKernelGGL(k4_dft, dim3(B_ * NF_), dim3(256), 0, stream,
                     ws, ws + OUTF_OFF_, out);
}

// Round 2
// 352.857 us; speedup vs baseline: 7.5238x; 7.5238x over previous
//
#include <hip/hip_runtime.h>
#include <math.h>

typedef unsigned short u16;
typedef unsigned int u32;

#define B_   256
#define F_   512
#define T_   81
#define WIN_ 1022
#define HOP_ 400
#define NF_  69
#define OUT_LEN_ 28550
#define SEG_ 1000
#define OVL_ 50

#define MA_  20736     // B_*T_
#define MB_  17664     // B_*NF_
#define K_   1024

// workspace byte offsets
#define SYNWIN_B   0u
#define HANN_B     4096u
#define BASA_B     8192u                      // 1024*1024 bf16 = 2 MiB
#define BASB_B     (BASA_B + 2097152u)
#define ABUF_B     (BASB_B + 2097152u)        // 20736*1024 bf16 = 42467328 B
#define TF_B       (ABUF_B + 42467328u)       // 20736*1024 bf16
#define OUTF_B     (TF_B + 42467328u)         // 256*28672 bf16
#define OUTF_STRIDE_ 28672
#define FBUF_B     ABUF_B                     // alias: Abuf dead after gemmA

typedef __attribute__((ext_vector_type(8))) short bf8_t;
typedef __attribute__((ext_vector_type(4))) float f4_t;
typedef const __attribute__((address_space(1))) void* as1cv;
typedef __attribute__((address_space(3))) void* as3v;

__device__ __forceinline__ float b2f(u16 v) {
  u32 u = ((u32)v) << 16; float f; __builtin_memcpy(&f, &u, 4); return f;
}
__device__ __forceinline__ u16 f2b(float f) {
  u32 u; __builtin_memcpy(&u, &f, 4);
  return (u16)((u + 0x7fffu + ((u >> 16) & 1u)) >> 16);
}

// ---------------------------------------------------------------------------
// K1: synthesis window + hann tables
// ---------------------------------------------------------------------------
__global__ __launch_bounds__(256) void k1_tables(float* __restrict__ ws) {
  int i = blockIdx.x * 256 + threadIdx.x;
  if (i >= WIN_) return;
  const float twopi_N = 6.283185307179586f / (float)WIN_;
  float w = 0.5f - 0.5f * cosf(twopi_N * (float)i);
  int j = i % HOP_;
  float a = 0.5f - 0.5f * cosf(twopi_N * (float)j);
  float b = 0.5f - 0.5f * cosf(twopi_N * (float)(j + 400));
  float d = a * a + b * b;
  if (j + 800 < WIN_) {
    float c = 0.5f - 0.5f * cosf(twopi_N * (float)(j + 800));
    d += c * c;
  }
  ((float*)((char*)ws + SYNWIN_B))[i] = w / d;
  ((float*)((char*)ws + HANN_B))[i]   = w;
}

// ---------------------------------------------------------------------------
// BasisA[n][2k+j]: iDFT basis, transposed (n-major), synwin/N and c_k folded.
// ---------------------------------------------------------------------------
__global__ __launch_bounds__(256) void gen_basisA(const float* __restrict__ synwin,
                                                  u16* __restrict__ BA) {
  int n = blockIdx.x;                 // 0..1023
  float scale = (n < WIN_) ? synwin[n] * (1.0f / (float)WIN_) : 0.f;
  for (int k = threadIdx.x; k < 512; k += 256) {
    int m = (k * n) % WIN_;
    float ang = 6.283185307179586f * (float)m / (float)WIN_;
    float s, c; __sincosf(ang, &s, &c);
    bool edge = (k == 0) || (k == 511);
    float ck = edge ? 1.f : 2.f;
    float re = scale * ck * c;
    float im = edge ? 0.f : -scale * ck * s;
    BA[(size_t)n * K_ + 2 * k]     = f2b(re);
    BA[(size_t)n * K_ + 2 * k + 1] = f2b(im);
  }
}

// ---------------------------------------------------------------------------
// BasisB[2k+j][w]: forward DFT basis, transposed (output-col-major).
// ---------------------------------------------------------------------------
__global__ __launch_bounds__(256) void gen_basisB(u16* __restrict__ BB) {
  int k = blockIdx.x;                 // 0..511
  for (int w = threadIdx.x; w < K_; w += 256) {
    float re = 0.f, im = 0.f;
    if (w < WIN_) {
      int m = (k * w) % WIN_;
      float ang = 6.283185307179586f * (float)m / (float)WIN_;
      float s, c; __sincosf(ang, &s, &c);
      re = c; im = -s;
    }
    BB[(size_t)(2 * k)     * K_ + w] = f2b(re);
    BB[(size_t)(2 * k + 1) * K_ + w] = f2b(im);
  }
}

// ---------------------------------------------------------------------------
// prep1: x[b][k][t][2] fp32 -> Abuf[b*81+t][2k+j] bf16 (LDS-tiled transpose)
// ---------------------------------------------------------------------------
__global__ __launch_bounds__(256) void prep1(const float* __restrict__ x,
                                             u16* __restrict__ Abuf) {
  __shared__ float2 tile[32][33];
  int k0 = blockIdx.x * 32, t0 = blockIdx.y * 32, b = blockIdx.z;
  int c = threadIdx.x & 31, rr = threadIdx.x >> 5;
  const float2* xp = (const float2*)x;
#pragma unroll
  for (int i = 0; i < 4; ++i) {
    int k = k0 + rr + 8 * i, t = t0 + c;
    float2 v = make_float2(0.f, 0.f);
    if (t < T_) v = xp[(size_t)(b * F_ + k) * T_ + t];
    tile[rr + 8 * i][c] = v;
  }
  __syncthreads();
#pragma unroll
  for (int i = 0; i < 4; ++i) {
    int t = t0 + rr + 8 * i, kc = c;
    if (t < T_) {
      float2 v = tile[kc][rr + 8 * i];
      u32 packed = (u32)f2b(v.x) | ((u32)f2b(v.y) << 16);
      *(u32*)&Abuf[(size_t)(b * T_ + t) * K_ + 2 * (k0 + kc)] = packed;
    }
  }
}

// ---------------------------------------------------------------------------
// GEMM: C[M x 1024] = A[M x 1024] * Bt[1024 x 1024]^T  (Bt stored n-major)
// 128x128 tile, 4 waves (2x2 of 64x64), mfma 16x16x32 bf16,
// global_load_lds width-16 staging (m97 structure).
// EPI 0: store bf16 to TF.  EPI 1: LDS-repack, store float2 scatter to d_out.
// ---------------------------------------------------------------------------
template <int EPI>
__global__ __launch_bounds__(256) void gemm_bf16(const u16* __restrict__ A,
                                                 const u16* __restrict__ Bt,
                                                 void* __restrict__ Cout) {
  __shared__ u16 sA[128 * 32];
  __shared__ u16 sB[128 * 32];
  const int tid = threadIdx.x;
  const int lane = tid & 63, wv = tid >> 6;
  const int bm = blockIdx.x * 128, bn = blockIdx.y * 128;

  // staging: wave wv loads chunks c0, c0+1 of each tile (16 rows x 32 cols each)
  const int c0 = wv * 2;
  const int srow = 16 * c0 + (lane >> 2);
  const int scol = (lane & 3) * 8;
  const u16* gA0 = A  + (size_t)(bm + srow) * K_ + scol;
  const u16* gA1 = gA0 + (size_t)16 * K_;
  const u16* gB0 = Bt + (size_t)(bn + srow) * K_ + scol;
  const u16* gB1 = gB0 + (size_t)16 * K_;
  u16* lA0 = sA + c0 * 512;
  u16* lA1 = lA0 + 512;
  u16* lB0 = sB + c0 * 512;
  u16* lB1 = lB0 + 512;

  f4_t acc[4][4];
#pragma unroll
  for (int i = 0; i < 4; ++i)
#pragma unroll
    for (int j = 0; j < 4; ++j) acc[i][j] = (f4_t){0.f, 0.f, 0.f, 0.f};

  const int wm = (wv >> 1) * 64, wn = (wv & 1) * 64;
  const int frow = lane & 15;
  const int fcol = (lane >> 4) * 8;

  for (int k0 = 0; k0 < K_; k0 += 32) {
    __builtin_amdgcn_global_load_lds((as1cv)(const void*)(gA0 + k0), (as3v)lA0, 16, 0, 0);
    __builtin_amdgcn_global_load_lds((as1cv)(const void*)(gA1 + k0), (as3v)lA1, 16, 0, 0);
    __builtin_amdgcn_global_load_lds((as1cv)(const void*)(gB0 + k0), (as3v)lB0, 16, 0, 0);
    __builtin_amdgcn_global_load_lds((as1cv)(const void*)(gB1 + k0), (as3v)lB1, 16, 0, 0);
    __builtin_amdgcn_s_waitcnt(0x0f70);  // vmcnt(0)
    __syncthreads();

    bf8_t af[4], bq[4];
#pragma unroll
    for (int i = 0; i < 4; ++i)
      af[i] = *(const bf8_t*)&sA[(wm + 16 * i + frow) * 32 + fcol];
#pragma unroll
    for (int j = 0; j < 4; ++j)
      bq[j] = *(const bf8_t*)&sB[(wn + 16 * j + frow) * 32 + fcol];
#pragma unroll
    for (int i = 0; i < 4; ++i)
#pragma unroll
      for (int j = 0; j < 4; ++j)
        acc[i][j] = __builtin_amdgcn_mfma_f32_16x16x32_bf16(af[i], bq[j], acc[i][j], 0, 0, 0);
    __syncthreads();
  }

  if (EPI == 0) {
    // store bf16 to TF[row][col], row-major stride 1024
    u16* C = (u16*)Cout;
#pragma unroll
    for (int i = 0; i < 4; ++i)
#pragma unroll
      for (int j = 0; j < 4; ++j) {
        int colg = bn + wn + 16 * j + frow;
#pragma unroll
        for (int r = 0; r < 4; ++r) {
          int rowg = bm + wm + 16 * i + (lane >> 4) * 4 + r;
          C[(size_t)rowg * K_ + colg] = f2b(acc[i][j][r]);
        }
      }
  } else {
    // per-wave LDS repack -> coalesced float2 scatter into out[b][k][f][2]
    float* out = (float*)Cout;
    float* ep = ((wv & 2) ? (float*)sB : (float*)sA) + (wv & 1) * 1024;  // 64x16 f32
    for (int j = 0; j < 4; ++j) {
#pragma unroll
      for (int i = 0; i < 4; ++i)
#pragma unroll
        for (int r = 0; r < 4; ++r) {
          int row64 = 16 * i + (lane >> 4) * 4 + r;
          ep[row64 * 16 + frow] = acc[i][j][r];
        }
      __syncthreads();
      int m = bm + wm + lane;          // frame index
      int b = m / NF_;
      int f = m - b * NF_;
      int colbase = bn + wn + 16 * j;  // even
#pragma unroll
      for (int a = 0; a < 8; ++a) {
        int k = (colbase >> 1) + a;
        float2 v = make_float2(ep[lane * 16 + 2 * a], ep[lane * 16 + 2 * a + 1]);
        ((float2*)out)[((size_t)b * F_ + k) * NF_ + f] = v;
      }
      __syncthreads();
    }
  }
}

// ---------------------------------------------------------------------------
// fold: overlap-add gather + keep + crossfade (bf16 in / bf16 out)
// ---------------------------------------------------------------------------
__device__ __forceinline__ float sigval(const u16* __restrict__ tfb, int i) {
  int t1 = i / HOP_; if (t1 > T_ - 1) t1 = T_ - 1;
  int t0 = (i >= WIN_) ? (i - (WIN_ - 1) + HOP_ - 1) / HOP_ : 0;
  float acc = 0.f;
  for (int t = t0; t <= t1; ++t)
    acc += b2f(tfb[(size_t)t * K_ + (i - t * HOP_)]);
  return acc;
}

__global__ __launch_bounds__(256) void k3_fold(const u16* __restrict__ tf,
                                               u16* __restrict__ outf) {
  int id = blockIdx.x * 256 + threadIdx.x;
  if (id >= B_ * OUT_LEN_) return;
  int b = id / OUT_LEN_;
  int p = id - b * OUT_LEN_;
  int s, r;
  if (p < SEG_) { s = 0; r = p; }
  else {
    int q = p - SEG_;
    s = q / (SEG_ - OVL_) + 1;
    r = OVL_ + (q - (s - 1) * (SEG_ - OVL_));
  }
  const u16* tfb = tf + (size_t)b * T_ * K_;
  float val;
  if (r >= SEG_ - OVL_ && s <= 28) {
    float dec = (float)(SEG_ - r) * (1.f / (float)OVL_);
    float inc = (float)(r - (SEG_ - OVL_ - 1)) * (1.f / (float)OVL_);
    float v1 = sigval(tfb, s * 1100 + r);
    float v2 = sigval(tfb, (s + 1) * 1100 + (r - (SEG_ - OVL_)));
    val = dec * v1 + inc * v2;
  } else {
    val = sigval(tfb, s * 1100 + r);
  }
  outf[(size_t)b * OUTF_STRIDE_ + p] = f2b(val);
}

// ---------------------------------------------------------------------------
// prep2: outf bf16 -> Fbuf[b*69+f][w] = outf[b][f*400+w]*hann[w], bf16
// ---------------------------------------------------------------------------
__global__ __launch_bounds__(256) void prep2(const u16* __restrict__ outf,
                                             const float* __restrict__ hann,
                                             u16* __restrict__ Fbuf) {
  int bf = blockIdx.x;
  int b = bf / NF_, f = bf - b * NF_;
  int w0 = threadIdx.x * 4;
  const u16* src = outf + (size_t)b * OUTF_STRIDE_ + f * HOP_ + w0;
  ushort4 in = *(const ushort4*)src;
  u16 o[4];
  float vv[4] = {b2f(in.x), b2f(in.y), b2f(in.z), b2f(in.w)};
#pragma unroll
  for (int ii = 0; ii < 4; ++ii) {
    int w = w0 + ii;
    o[ii] = (w < WIN_) ? f2b(vv[ii] * hann[w]) : (u16)0;
  }
  *(ushort4*)&Fbuf[(size_t)bf * K_ + w0] = make_ushort4(o[0], o[1], o[2], o[3]);
}

// ---------------------------------------------------------------------------
extern "C" void kernel_launch(void* const* d_in, const int* in_sizes, int n_in,
                              void* d_out, int out_size, void* d_ws, size_t ws_size,
                              hipStream_t stream) {
  const float* x = (const float*)d_in[0];
  char* ws = (char*)d_ws;
  float* synwin = (float*)(ws + SYNWIN_B);
  float* hann   = (float*)(ws + HANN_B);
  u16* BA   = (u16*)(ws + BASA_B);
  u16* BB   = (u16*)(ws + BASB_B);
  u16* Abuf = (u16*)(ws + ABUF_B);
  u16* TF   = (u16*)(ws + TF_B);
  u16* outf = (u16*)(ws + OUTF_B);
  u16* Fbuf = (u16*)(ws + FBUF_B);
  float* out = (float*)d_out;

  hipLaunchKernelGGL(k1_tables, dim3(4), dim3(256), 0, stream, (float*)ws);
  hipLaunchKernelGGL(gen_basisA, dim3(1024), dim3(256), 0, stream, synwin, BA);
  hipLaunchKernelGGL(gen_basisB, dim3(512), dim3(256), 0, stream, BB);
  hipLaunchKernelGGL(prep1, dim3(16, 3, 256), dim3(256), 0, stream, x, Abuf);
  hipLaunchKernelGGL((gemm_bf16<0>), dim3(MA_ / 128, 8), dim3(256), 0, stream,
                     Abuf, BA, (void*)TF);
  int n3 = B_ * OUT_LEN_;
  hipLaunchKernelGGL(k3_fold, dim3((n3 + 255) / 256), dim3(256), 0, stream, TF, outf);
  hipLaunchKernelGGL(prep2, dim3(MB_), dim3(256), 0, stream, outf, hann, Fbuf);
  hipLaunchKernelGGL((gemm_bf16<1>), dim3(MB_ / 128, 8), dim3(256), 0, stream,
                     Fbuf, BB, (void*)d_out);
}